// Round 8
// baseline (358.301 us; speedup 1.0000x reference)
//
#include <hip/hip_runtime.h>

#define NN 100000
#define NE 1600000
#define BN_EPS 1e-5f
#define NBKT 6250         // buckets of 16 nodes: 6250*16 = 100000 exactly
#define NBLK 400          // binning blocks
#define CHUNK 4000        // edges per binning block (400*4000 = NE)
#define H2STR 40          // LDS h2^T row stride in shorts (80B, 16B-aligned rows)
#define NFRAG 48          // packed weight fragments

typedef short s8v __attribute__((ext_vector_type(8)));
typedef float f4v __attribute__((ext_vector_type(4)));

__device__ __forceinline__ float bf2f(unsigned short u) {
  union { unsigned u; float f; } v; v.u = ((unsigned)u) << 16; return v.f;
}
// round-half-up bf16: identical to RNE except on exact ties (prob 2^-16)
__device__ __forceinline__ unsigned short f2bf(float f) {
  union { float f; unsigned u; } v; v.f = f;
  return (unsigned short)((v.u + 0x8000u) >> 16);
}
__device__ __forceinline__ s8v ldfrag(const unsigned short* __restrict__ pack,
                                      int f, int lane) {
  return *(const s8v*)(pack + ((size_t)f * 64 + lane) * 8);
}

#define MFMA16(a, b, c) __builtin_amdgcn_mfma_f32_16x16x32_bf16((a), (b), (c), 0, 0, 0)

// ---------------------------------------------------------------------------
// Weight pack (one-shot) + BN-partial zeroing.
// frag map: 0..7 W1 top | 8..15 W1 bot | 16..23 W2 | 24..39 W3 | 40..47 W4
// ---------------------------------------------------------------------------
__global__ __launch_bounds__(256) void pack_kernel(
    const float* __restrict__ W1, const float* __restrict__ W2,
    const float* __restrict__ W3, const float* __restrict__ W4,
    unsigned short* __restrict__ pack, float* __restrict__ part)
{
  if (threadIdx.x < 128) part[threadIdx.x] = 0.f;
  for (int it = threadIdx.x; it < NFRAG * 64; it += 256) {
    const int f = it >> 6;
    const int lane = it & 63;
    const int q = lane >> 4, r = lane & 15;
    const float* src; int rowoff, fi;
    if (f < 8)       { src = W1; rowoff = 0;  fi = f; }
    else if (f < 16) { src = W1; rowoff = 64; fi = f - 8; }
    else if (f < 24) { src = W2; rowoff = 0;  fi = f - 16; }
    else if (f < 40) { src = W3; rowoff = 0;  fi = f - 24; }
    else             { src = W4; rowoff = 0;  fi = f - 40; }
    const int kk = fi >> 2, nt = fi & 3;
    unsigned short tmp[8];
#pragma unroll
    for (int j = 0; j < 8; ++j)
      tmp[j] = f2bf(src[(size_t)(rowoff + kk * 32 + q * 8 + j) * 64 + nt * 16 + r]);
    *(s8v*)(pack + ((size_t)f * 64 + lane) * 8) = *(const s8v*)tmp;
  }
}

// ---------------------------------------------------------------------------
// Pre-GEMM: F = X@W1top + b1 (bias folded), G = X@W1bot, XB = bf16(X)
// all bf16 row-major [NN][64]
// ---------------------------------------------------------------------------
__global__ __launch_bounds__(256) void pre_gemm_kernel(
    const float* __restrict__ x, const unsigned short* __restrict__ pack,
    const float* __restrict__ b1,
    unsigned short* __restrict__ F, unsigned short* __restrict__ G,
    unsigned short* __restrict__ XB)
{
  const int lane = threadIdx.x & 63;
  const int wv   = threadIdx.x >> 6;
  const int q    = lane >> 4;
  const int r    = lane & 15;
  const int nw   = gridDim.x * 4;
  const int wid  = blockIdx.x * 4 + wv;

  s8v Bt[2][4], Bb[2][4];
#pragma unroll
  for (int kk = 0; kk < 2; ++kk)
#pragma unroll
    for (int nt = 0; nt < 4; ++nt) {
      Bt[kk][nt] = ldfrag(pack, kk * 4 + nt, lane);
      Bb[kk][nt] = ldfrag(pack, 8 + kk * 4 + nt, lane);
    }
  float b1c[4];
#pragma unroll
  for (int nt = 0; nt < 4; ++nt) b1c[nt] = b1[nt * 16 + r];

  for (int t = wid; t < NN / 16; t += nw) {
    const int n = t * 16 + r;
    const f4v* xp = (const f4v*)(x + (size_t)n * 64);
    f4v x0 = xp[q * 2],     x1 = xp[q * 2 + 1];
    f4v x2 = xp[8 + q * 2], x3 = xp[8 + q * 2 + 1];
    s8v a0, a1v;
#pragma unroll
    for (int j = 0; j < 4; ++j) {
      a0[j]      = (short)f2bf(x0[j]);
      a0[4 + j]  = (short)f2bf(x1[j]);
      a1v[j]     = (short)f2bf(x2[j]);
      a1v[4 + j] = (short)f2bf(x3[j]);
    }
    // XB: row n, cols q*8.. and 32+q*8..
    *(s8v*)(XB + (size_t)n * 64 + q * 8)      = a0;
    *(s8v*)(XB + (size_t)n * 64 + 32 + q * 8) = a1v;

    f4v aF[4], aG[4];
#pragma unroll
    for (int nt = 0; nt < 4; ++nt) {
      f4v c = {0.f, 0.f, 0.f, 0.f};
      c = MFMA16(a0,  Bt[0][nt], c);
      c = MFMA16(a1v, Bt[1][nt], c);
      aF[nt] = c;
      f4v d = {0.f, 0.f, 0.f, 0.f};
      d = MFMA16(a0,  Bb[0][nt], d);
      d = MFMA16(a1v, Bb[1][nt], d);
      aG[nt] = d;
    }
#pragma unroll
    for (int nt = 0; nt < 4; ++nt)
#pragma unroll
      for (int rg = 0; rg < 4; ++rg) {
        const size_t idx = (size_t)(t * 16 + q * 4 + rg) * 64 + nt * 16 + r;
        F[idx] = f2bf(aF[nt][rg] + b1c[nt]);
        G[idx] = f2bf(aG[nt][rg]);
      }
  }
}

// ---------------------------------------------------------------------------
// Binning pass 1: per-block LDS histogram over 6250 buckets (bucket = dst>>4)
// -> hmat TRANSPOSED [bucket][block]
// ---------------------------------------------------------------------------
__global__ __launch_bounds__(256) void hist_kernel(
    const int* __restrict__ dstp, int* __restrict__ hmat)
{
  __shared__ int lh[NBKT];
  const int t = threadIdx.x;
  for (int i = t; i < NBKT; i += 256) lh[i] = 0;
  __syncthreads();
  const int base = blockIdx.x * CHUNK;
#pragma unroll
  for (int i = 0; i < 16; ++i) {
    const int o = i * 256 + t;
    if (o < CHUNK) atomicAdd(&lh[dstp[base + o] >> 4], 1);
  }
  __syncthreads();
  for (int i = t; i < NBKT; i += 256)
    hmat[(size_t)i * NBLK + blockIdx.x] = lh[i];
}

// ---------------------------------------------------------------------------
// Binning pass 2a: per-bucket exclusive scan over blocks (contiguous int4)
// ---------------------------------------------------------------------------
__global__ __launch_bounds__(256) void scan_col_kernel(
    int* __restrict__ hmat, int* __restrict__ total)
{
  const int b = blockIdx.x * 256 + threadIdx.x;
  if (b >= NBKT) return;
  int4* hp = (int4*)(hmat + (size_t)b * NBLK);
  int run = 0;
#pragma unroll 4
  for (int i = 0; i < NBLK / 4; ++i) {
    int4 v = hp[i]; int4 o;
    o.x = run; run += v.x;
    o.y = run; run += v.y;
    o.z = run; run += v.z;
    o.w = run; run += v.w;
    hp[i] = o;
  }
  total[b] = run;
}

// ---------------------------------------------------------------------------
// Binning pass 2b: exclusive scan of total[6250] -> boffs[6251] (1 block/1024)
// ---------------------------------------------------------------------------
__global__ __launch_bounds__(1024) void scan_total_kernel(
    const int* __restrict__ total, int* __restrict__ boffs)
{
  const int tid = threadIdx.x;
  const int lane = tid & 63, wv = tid >> 6;        // 16 waves
  __shared__ int wsum[16], wbase[16];
  int v[7]; int s = 0;
#pragma unroll
  for (int j = 0; j < 7; ++j) {
    const int idx = tid * 7 + j;
    v[j] = (idx < NBKT) ? total[idx] : 0;
    s += v[j];
  }
  int inc = s;
#pragma unroll
  for (int d = 1; d < 64; d <<= 1) { int t = __shfl_up(inc, d, 64); if (lane >= d) inc += t; }
  if (lane == 63) wsum[wv] = inc;
  __syncthreads();
  if (tid == 0) { int run = 0; for (int k = 0; k < 16; ++k) { wbase[k] = run; run += wsum[k]; } }
  __syncthreads();
  int run = wbase[wv] + inc - s;
#pragma unroll
  for (int j = 0; j < 7; ++j) {
    const int idx = tid * 7 + j;
    if (idx < NBKT) boffs[idx] = run;
    run += v[j];
  }
  if (tid == 0) boffs[NBKT] = NE;
}

// ---------------------------------------------------------------------------
// Binning pass 3: scatter edges to bucket order; LDS cursors only.
// word = (src << 4) | (dst & 15).  NO per-node sort needed: the indicator
// MFMA in edge_agg handles arbitrary order within a 16-node group.
// ---------------------------------------------------------------------------
__global__ __launch_bounds__(256) void scatter_kernel(
    const int* __restrict__ srcp, const int* __restrict__ dstp,
    const int* __restrict__ hmat, const int* __restrict__ boffs,
    int* __restrict__ ebuf)
{
  __shared__ int lcur[NBKT];
  const int t = threadIdx.x;
  for (int i = t; i < NBKT; i += 256)
    lcur[i] = boffs[i] + hmat[(size_t)i * NBLK + blockIdx.x];
  __syncthreads();
  const int base = blockIdx.x * CHUNK;
#pragma unroll
  for (int i = 0; i < 16; ++i) {
    const int o = i * 256 + t;
    if (o < CHUNK) {
      const int d = dstp[base + o];
      const int s = srcp[base + o];
      const int p = atomicAdd(&lcur[d >> 4], 1);
      ebuf[p] = (s << 4) | (d & 15);
    }
  }
}

// ---------------------------------------------------------------------------
// Edge MLP + aggregation, RMW-free: one wave per 16-node bucket/group.
// h1 = prelu(F[dst]+G[src]) (b1 pre-folded into F); h2^T via transposed MFMA;
// AGG += S^T @ H2 with 0/1 indicator; AGPR accumulator; bf16 store per node.
// ---------------------------------------------------------------------------
__global__ __launch_bounds__(256) void edge_agg_kernel(
    const unsigned short* __restrict__ F, const unsigned short* __restrict__ G,
    const int* __restrict__ ebuf, const int* __restrict__ boffs,
    const unsigned short* __restrict__ pack,
    const float* __restrict__ a1p,
    const float* __restrict__ b2, const float* __restrict__ a2p,
    unsigned short* __restrict__ aggb)
{
  const int lane = threadIdx.x & 63;
  const int wv   = threadIdx.x >> 6;
  const int q    = lane >> 4;
  const int r    = lane & 15;

  __shared__ __align__(16) unsigned short h2t[4][64 * H2STR]; // per-wave h2^T
  __shared__ __align__(16) unsigned short dbf[4][32];          // per-wave dloc
  unsigned short* hb = h2t[wv];
  unsigned short* db = dbf[wv];

  const int g = blockIdx.x * 4 + wv;
  if (g >= NBKT) return;                      // no barriers below: safe

  s8v W2T[2][4];
#pragma unroll
  for (int kk = 0; kk < 2; ++kk)
#pragma unroll
    for (int ot = 0; ot < 4; ++ot)
      W2T[kk][ot] = ldfrag(pack, 16 + kk * 4 + ot, lane);

  float b2v[4][4];
#pragma unroll
  for (int ot = 0; ot < 4; ++ot)
#pragma unroll
    for (int rg = 0; rg < 4; ++rg) b2v[ot][rg] = b2[ot * 16 + q * 4 + rg];
  const float al1 = a1p[0];
  const float al2 = a2p[0];

  const int start = boffs[g], end = boffs[g + 1];
  const int nbase = g * 16;

  f4v acc[4];
#pragma unroll
  for (int ft = 0; ft < 4; ++ft) acc[ft] = (f4v){0.f, 0.f, 0.f, 0.f};

  for (int c0 = start; c0 < end; c0 += 32) {
#pragma unroll
    for (int tu = 0; tu < 2; ++tu) {
      const int e  = c0 + tu * 16 + r;
      const int ec = e < end ? e : end - 1;
      const int w  = ebuf[ec];
      const int dl = w & 15;
      const int sn = w >> 4;
      const int dn = nbase + dl;
      if (q == 0) db[tu * 16 + r] = (e < end) ? (unsigned short)dl
                                              : (unsigned short)0xFF;

      s8v fa = *(const s8v*)(F + (size_t)dn * 64 + q * 8);
      s8v fb = *(const s8v*)(F + (size_t)dn * 64 + 32 + q * 8);
      s8v ga = *(const s8v*)(G + (size_t)sn * 64 + q * 8);
      s8v gb = *(const s8v*)(G + (size_t)sn * 64 + 32 + q * 8);

      s8v p0, p1;
#pragma unroll
      for (int j = 0; j < 8; ++j) {
        float v = bf2f((unsigned short)fa[j]) + bf2f((unsigned short)ga[j]);
        v = v >= 0.f ? v : al1 * v;
        p0[j] = (short)f2bf(v);
        float u = bf2f((unsigned short)fb[j]) + bf2f((unsigned short)gb[j]);
        u = u >= 0.f ? u : al1 * u;
        p1[j] = (short)f2bf(u);
      }

      // h2^T = prelu(W2^T @ h1^T + b2): C col=edge, row=q*4+rg=feature
#pragma unroll
      for (int ot = 0; ot < 4; ++ot) {
        f4v c = {0.f, 0.f, 0.f, 0.f};
        c = MFMA16(W2T[0][ot], p0, c);
        c = MFMA16(W2T[1][ot], p1, c);
#pragma unroll
        for (int rg = 0; rg < 4; ++rg) {
          float v = c[rg] + b2v[ot][rg];
          v = v >= 0.f ? v : al2 * v;
          hb[(ot * 16 + q * 4 + rg) * H2STR + tu * 16 + r] = f2bf(v);
        }
      }
    }

    // S^T indicator A-frag: A[m=node=r][k=edge=q*8+j]
    s8v dv = *(const s8v*)(db + q * 8);
    s8v sA;
#pragma unroll
    for (int j = 0; j < 8; ++j)
      sA[j] = (short)(((int)(unsigned short)dv[j] == r) ? 0x3F80 : 0);

    // AGG += S^T @ H2 : B[k=edge=q*8+j][n=feat=ft*16+r]
#pragma unroll
    for (int ft = 0; ft < 4; ++ft) {
      s8v bf = *(const s8v*)(hb + (ft * 16 + r) * H2STR + q * 8);
      acc[ft] = MFMA16(sA, bf, acc[ft]);
    }
  }

  // flush: one bf16 store per (node, feature)
#pragma unroll
  for (int ft = 0; ft < 4; ++ft)
#pragma unroll
    for (int rg = 0; rg < 4; ++rg) {
      const int node = nbase + q * 4 + rg;
      aggb[(size_t)node * 64 + ft * 16 + r] = f2bf(acc[ft][rg]);
    }
}

// ---------------------------------------------------------------------------
// Node MLP: z = prelu(prelu(cat(x,agg) @ W3 + b3) @ W4 + b4, a_blk)
// inputs XB / aggb already bf16 in fragment-ready row-major layout
// ---------------------------------------------------------------------------
__global__ __launch_bounds__(256) void node_mlp_kernel(
    const unsigned short* __restrict__ XB,
    const unsigned short* __restrict__ aggb,
    const unsigned short* __restrict__ pack,
    const float* __restrict__ b3, const float* __restrict__ a3p,
    const float* __restrict__ b4, const float* __restrict__ ablkp,
    float* __restrict__ zout,
    float* __restrict__ part)
{
  const int lane = threadIdx.x & 63;
  const int wv   = threadIdx.x >> 6;
  const int q    = lane >> 4;
  const int r    = lane & 15;
  const int nw   = gridDim.x * 4;
  const int wid  = blockIdx.x * 4 + wv;

  s8v B3f[4][4];
  s8v B4f[2][4];
#pragma unroll
  for (int kk = 0; kk < 4; ++kk)
#pragma unroll
    for (int nt = 0; nt < 4; ++nt)
      B3f[kk][nt] = ldfrag(pack, 24 + kk * 4 + nt, lane);
#pragma unroll
  for (int kk = 0; kk < 2; ++kk)
#pragma unroll
    for (int nt = 0; nt < 4; ++nt)
      B4f[kk][nt] = ldfrag(pack, 40 + kk * 4 + nt, lane);

  float bias3[4], bias4[4];
#pragma unroll
  for (int nt = 0; nt < 4; ++nt) { bias3[nt] = b3[nt * 16 + r]; bias4[nt] = b4[nt * 16 + r]; }
  const float al3 = a3p[0];
  const float alb = ablkp[0];

  __shared__ __align__(16) unsigned short hbuf[4][16 * 72];
  unsigned short* hb = hbuf[wv];

  float bs[4] = {0.f, 0.f, 0.f, 0.f};
  float bq[4] = {0.f, 0.f, 0.f, 0.f};

  for (int t = wid; t < NN / 16; t += nw) {
    const int n = t * 16 + r;
    const s8v* xn = (const s8v*)(XB + (size_t)n * 64);
    const s8v* an = (const s8v*)(aggb + (size_t)n * 64);
    s8v a0  = xn[q];
    s8v a1v = xn[q + 4];
    s8v a2v = an[q];
    s8v a3v = an[q + 4];

    f4v acc[4];
#pragma unroll
    for (int nt = 0; nt < 4; ++nt) {
      f4v c = {0.f, 0.f, 0.f, 0.f};
      c = MFMA16(a0,  B3f[0][nt], c);
      c = MFMA16(a1v, B3f[1][nt], c);
      c = MFMA16(a2v, B3f[2][nt], c);
      c = MFMA16(a3v, B3f[3][nt], c);
      acc[nt] = c;
    }

#pragma unroll
    for (int nt = 0; nt < 4; ++nt)
#pragma unroll
      for (int rg = 0; rg < 4; ++rg) {
        float v = acc[nt][rg] + bias3[nt];
        v = v >= 0.f ? v : al3 * v;
        hb[(q * 4 + rg) * 72 + nt * 16 + r] = f2bf(v);
      }
    s8v p0 = *(const s8v*)(hb + r * 72 + q * 8);
    s8v p1 = *(const s8v*)(hb + r * 72 + 32 + q * 8);

    f4v acc2[4];
#pragma unroll
    for (int nt = 0; nt < 4; ++nt) {
      f4v c = {0.f, 0.f, 0.f, 0.f};
      c = MFMA16(p0, B4f[0][nt], c);
      c = MFMA16(p1, B4f[1][nt], c);
      acc2[nt] = c;
    }

#pragma unroll
    for (int nt = 0; nt < 4; ++nt)
#pragma unroll
      for (int rg = 0; rg < 4; ++rg) {
        float v = acc2[nt][rg] + bias4[nt];
        v = v >= 0.f ? v : alb * v;
        const int row = t * 16 + q * 4 + rg;
        zout[(size_t)row * 64 + nt * 16 + r] = v;
        bs[nt] += v;
        bq[nt] += v * v;
      }
  }

#pragma unroll
  for (int nt = 0; nt < 4; ++nt) {
    float s = bs[nt];
    s += __shfl_xor(s, 16, 64);
    s += __shfl_xor(s, 32, 64);
    float ss = bq[nt];
    ss += __shfl_xor(ss, 16, 64);
    ss += __shfl_xor(ss, 32, 64);
    if (q == 0) {
      atomicAdd(&part[nt * 16 + r], s);
      atomicAdd(&part[64 + nt * 16 + r], ss);
    }
  }
}

// ---------------------------------------------------------------------------
// BatchNorm finalize (in-place on d_out)
// ---------------------------------------------------------------------------
__global__ __launch_bounds__(256) void bn_kernel(
    float* __restrict__ out,
    const float* __restrict__ part,
    const float* __restrict__ gamma,
    const float* __restrict__ beta)
{
  const size_t i = (size_t)blockIdx.x * blockDim.x + threadIdx.x;
  if (i * 4 >= (size_t)NN * 64) return;
  float4 v = ((const float4*)out)[i];
  float e[4] = {v.x, v.y, v.z, v.w};
  const int f0 = (int)((i * 4) & 63);
  const float inv_n = 1.0f / (float)NN;
#pragma unroll
  for (int j = 0; j < 4; ++j) {
    const int f = f0 + j;
    const float mean = part[f] * inv_n;
    const float var  = part[64 + f] * inv_n - mean * mean;
    const float sc = rsqrtf(var + BN_EPS) * gamma[f];
    const float sh = beta[f] - mean * sc;
    e[j] = e[j] * sc + sh;
  }
  ((float4*)out)[i] = make_float4(e[0], e[1], e[2], e[3]);
}

extern "C" void kernel_launch(void* const* d_in, const int* in_sizes, int n_in,
                              void* d_out, int out_size, void* d_ws, size_t ws_size,
                              hipStream_t stream) {
  const float* x  = (const float*)d_in[0];
  const int* ei   = (const int*)d_in[1];
  const float* W1 = (const float*)d_in[2];
  const float* b1 = (const float*)d_in[3];
  const float* a1 = (const float*)d_in[4];
  const float* W2 = (const float*)d_in[5];
  const float* b2 = (const float*)d_in[6];
  const float* a2 = (const float*)d_in[7];
  const float* W3 = (const float*)d_in[8];
  const float* b3 = (const float*)d_in[9];
  const float* a3 = (const float*)d_in[10];
  const float* W4 = (const float*)d_in[11];
  const float* b4 = (const float*)d_in[12];
  const float* ab = (const float*)d_in[13];
  const float* gm = (const float*)d_in[14];
  const float* bt = (const float*)d_in[15];

  float* part          = (float*)d_ws;                   // [128] f32
  unsigned short* aggb = (unsigned short*)(part + 128);  // [NN*64] bf16
  unsigned short* F    = aggb + (size_t)NN * 64;         // [NN*64] bf16 (+b1)
  unsigned short* G    = F + (size_t)NN * 64;            // [NN*64] bf16
  unsigned short* XB   = G + (size_t)NN * 64;            // [NN*64] bf16
  int* hmat            = (int*)(XB + (size_t)NN * 64);   // [NBKT*NBLK]
  int* total           = hmat + (size_t)NBKT * NBLK;     // [NBKT]
  int* boffs           = total + NBKT;                   // [NBKT+1] (+pad)
  int* ebuf            = boffs + NBKT + 8;               // [NE]
  unsigned short* pack = (unsigned short*)(ebuf + NE);   // [NFRAG*64*8] bf16
  float* out           = (float*)d_out;

  const int* srcp = ei;        // edge_index[0] = src (x_j)
  const int* dstp = ei + NE;   // edge_index[1] = dst (x_i)

  pack_kernel<<<dim3(1), dim3(256), 0, stream>>>(W1, W2, W3, W4, pack, part);
  pre_gemm_kernel<<<dim3(391), dim3(256), 0, stream>>>(x, pack, b1, F, G, XB);
  hist_kernel<<<dim3(NBLK), dim3(256), 0, stream>>>(dstp, hmat);
  scan_col_kernel<<<dim3((NBKT + 255) / 256), dim3(256), 0, stream>>>(hmat, total);
  scan_total_kernel<<<dim3(1), dim3(1024), 0, stream>>>(total, boffs);
  scatter_kernel<<<dim3(NBLK), dim3(256), 0, stream>>>(srcp, dstp, hmat, boffs, ebuf);
  edge_agg_kernel<<<dim3((NBKT + 3) / 4), dim3(256), 0, stream>>>(
      F, G, ebuf, boffs, pack, a1, b2, a2, aggb);
  node_mlp_kernel<<<dim3(391), dim3(256), 0, stream>>>(
      XB, aggb, pack, b3, a3, b4, ab, out, part);
  bn_kernel<<<dim3(6250), dim3(256), 0, stream>>>(out, part, gm, bt);
}